// Round 4
// baseline (297.073 us; speedup 1.0000x reference)
//
#include <hip/hip_runtime.h>

#define B_DIM 2048
#define IN_DIM 1024
#define OUT_DIM 1024
#define K_KNOTS 20
#define KR (IN_DIM * K_KNOTS)   // 20480 reduction dim
#define TM 128
#define TN 128
#define BK 64
#define OUT_ELEMS (B_DIM * OUT_DIM)

#define NB_PAIRS (B_DIM * IN_DIM * K_KNOTS / 2)   // 20,971,520 bf16 pairs
#define NB_BASIS_BLK (NB_PAIRS / 256)             // 81920 blocks
#define NW4 (OUT_DIM * KR / 8)                    // 2,621,440 uint4 outputs
#define NB_W_BLK (NW4 / 256)                      // 10240 blocks

typedef __bf16 bf16x8 __attribute__((ext_vector_type(8)));
typedef float  f32x4  __attribute__((ext_vector_type(4)));

__device__ __forceinline__ unsigned short f2bf(float f) {
    unsigned int u = __float_as_uint(f);
    unsigned int r = u + 0x7fffu + ((u >> 16) & 1u);   // RNE; no NaN inputs here
    return (unsigned short)(r >> 16);
}

__device__ __forceinline__ unsigned int pack2(float lo, float hi) {
    return (unsigned int)f2bf(lo) | ((unsigned int)f2bf(hi) << 16);
}

__device__ __forceinline__ void async_load16(const void* g, void* l) {
    __builtin_amdgcn_global_load_lds(
        (const __attribute__((address_space(1))) void*)g,
        (__attribute__((address_space(3))) void*)l,
        16, 0, 0);
}

// ---------------- zero the output (atomic fallback path only) ----------------
__global__ void zero_out_kernel(float* out) {
    int idx = (blockIdx.x * 256 + threadIdx.x) * 4;
    float4 z = {0.f, 0.f, 0.f, 0.f};
    *(float4*)(out + idx) = z;
}

// ------- merged prep: basis bf16 (B,IN*K) + W fp32->bf16, one dispatch -------
__global__ void prep_kernel(const float* __restrict__ x,
                            const float4* __restrict__ Wsrc,
                            const float* __restrict__ knots,
                            unsigned int* __restrict__ basis_out,
                            uint4* __restrict__ w_out) {
    if (blockIdx.x < NB_BASIS_BLK) {
        // basis: one thread per bf16 PAIR (adjacent k values)
        unsigned int n = blockIdx.x * 256 + threadIdx.x;
        unsigned int p  = n % 10u;                      // which k-pair
        unsigned int bi = n / 10u;                      // b*1024 + i
        float xv   = x[bi];
        float invh = 1.0f / (knots[1] - knots[0]);
        float t0 = knots[2 * p], t1 = knots[2 * p + 1];
        float d0 = (xv - t0) * invh;
        float d1 = (xv - t1) * invh;
        float v0 = __expf(-0.5f * d0 * d0);
        float v1 = __expf(-0.5f * d1 * d1);
        basis_out[n] = pack2(v0, v1);
    } else {
        // wconv: one thread per 8 W elements
        unsigned int t = (blockIdx.x - NB_BASIS_BLK) * 256 + threadIdx.x;
        float4 a = Wsrc[2 * t];
        float4 b = Wsrc[2 * t + 1];
        uint4 o;
        o.x = pack2(a.x, a.y);
        o.y = pack2(a.z, a.w);
        o.z = pack2(b.x, b.y);
        o.w = pack2(b.z, b.w);
        w_out[t] = o;
    }
}

// ---------------- bf16 MFMA GEMM: C[b,o] += sum_r A[b,r]*W[o,r] --------------
// LDS XOR swizzle keeps ds_read side conflict-free (verified R2: conflicts=0).
// ATOMIC=false: each z-slice writes its own disjoint partial buffer (no RMW).
template <int KS, bool ATOMIC>
__global__ void __launch_bounds__(256)
kan_gemm(const unsigned short* __restrict__ Ab,   // (2048, 20480) bf16 row-major
         const unsigned short* __restrict__ Bb,   // (1024, 20480) bf16 row-major
         float* __restrict__ out) {               // out or partial base
    __shared__ __align__(16) unsigned short As[TM * BK];
    __shared__ __align__(16) unsigned short Bs[TN * BK];

    const int KPB = KR / KS;
    const int tid  = threadIdx.x;
    const int wave = tid >> 6;
    const int lane = tid & 63;
    const int wm = wave & 1;          // 2x2 wave grid -> each wave does 64x64
    const int wn = wave >> 1;
    const int m0 = blockIdx.x * TM;
    const int n0 = blockIdx.y * TN;
    const int k0 = blockIdx.z * KPB;

    const int srow = lane >> 3;                 // staging: row within 8-row chunk
    const int scol = ((lane & 7) ^ srow) * 8;   // staging: swizzled element col

    f32x4 acc[4][4];
#pragma unroll
    for (int i = 0; i < 4; ++i)
#pragma unroll
        for (int j = 0; j < 4; ++j) acc[i][j] = (f32x4){0.f, 0.f, 0.f, 0.f};

    for (int kt = 0; kt < KPB; kt += BK) {
        const int kb = k0 + kt;
        __syncthreads();   // previous iteration's ds_reads done before overwrite
#pragma unroll
        for (int c = 0; c < 4; ++c) {
            const int chunk = wave * 4 + c;            // 16 chunks of 8 rows
            const int r = chunk * 8 + srow;
            async_load16(Ab + (size_t)(m0 + r) * KR + kb + scol, &As[chunk * 512]);
            async_load16(Bb + (size_t)(n0 + r) * KR + kb + scol, &Bs[chunk * 512]);
        }
        __syncthreads();   // compiler drains vmcnt(0) before barrier

        const int quad = lane >> 4;
        const int r15  = lane & 15;
        const int r7   = lane & 7;
#pragma unroll
        for (int s = 0; s < 2; ++s) {
            const int cg = s * 4 + quad;               // colgroup 0..7
            const int xo = (cg ^ r7) * 8;              // unswizzled element offset
            bf16x8 af[4], bfv[4];
#pragma unroll
            for (int i = 0; i < 4; ++i) {
                af[i]  = *(const bf16x8*)&As[(wm * 64 + i * 16 + r15) * BK + xo];
                bfv[i] = *(const bf16x8*)&Bs[(wn * 64 + i * 16 + r15) * BK + xo];
            }
#pragma unroll
            for (int i = 0; i < 4; ++i)
#pragma unroll
                for (int j = 0; j < 4; ++j)
                    acc[i][j] = __builtin_amdgcn_mfma_f32_16x16x32_bf16(
                        af[i], bfv[j], acc[i][j], 0, 0, 0);
        }
    }

    // epilogue: C/D layout col=lane&15, row=(lane>>4)*4+reg
    float* dst = ATOMIC ? out : out + (size_t)blockIdx.z * OUT_ELEMS;
    const int quad = lane >> 4;
    const int col  = lane & 15;
#pragma unroll
    for (int i = 0; i < 4; ++i)
#pragma unroll
        for (int j = 0; j < 4; ++j)
#pragma unroll
            for (int r = 0; r < 4; ++r) {
                const int row = m0 + wm * 64 + i * 16 + quad * 4 + r;
                const int c   = n0 + wn * 64 + j * 16 + col;
                if (ATOMIC)
                    atomicAdd(&dst[(size_t)row * OUT_DIM + c], acc[i][j][r]);
                else
                    dst[(size_t)row * OUT_DIM + c] = acc[i][j][r];
            }
}

// ---------------- reduce KS partial slices -> out ----------------------------
template <int KS>
__global__ void kan_reduce(const float* __restrict__ part, float* __restrict__ out) {
    const int idx = (blockIdx.x * 256 + threadIdx.x) * 4;
    f32x4 s = *(const f32x4*)(part + idx);
#pragma unroll
    for (int z = 1; z < KS; ++z)
        s += *(const f32x4*)(part + (size_t)z * OUT_ELEMS + idx);
    *(f32x4*)(out + idx) = s;
}

// ---------------- fallback (ws too small): correctness-only fp32 -------------
__global__ void kan_fallback(const float* __restrict__ x,
                             const float* __restrict__ W,
                             const float* __restrict__ knots,
                             float* __restrict__ out) {
    __shared__ float basis[256 * K_KNOTS];
    const int b = blockIdx.x;
    const int o = blockIdx.y * blockDim.x + threadIdx.x;
    const float invh = 1.0f / (knots[1] - knots[0]);
    const float* w = W + (size_t)o * KR;
    float sum = 0.f;
    for (int i0 = 0; i0 < IN_DIM; i0 += 256) {
        __syncthreads();
        for (int idx = threadIdx.x; idx < 256 * K_KNOTS; idx += blockDim.x) {
            const int i = i0 + idx / K_KNOTS;
            const int k = idx % K_KNOTS;
            const float d = (x[(size_t)b * IN_DIM + i] - knots[k]) * invh;
            basis[idx] = __expf(-0.5f * d * d);
        }
        __syncthreads();
        for (int r = 0; r < 256 * K_KNOTS; ++r)
            sum += basis[r] * w[(size_t)i0 * K_KNOTS + r];
    }
    out[(size_t)b * OUT_DIM + o] = sum;
}

extern "C" void kernel_launch(void* const* d_in, const int* in_sizes, int n_in,
                              void* d_out, int out_size, void* d_ws, size_t ws_size,
                              hipStream_t stream) {
    const float* x     = (const float*)d_in[0];
    const float* W     = (const float*)d_in[1];
    const float* knots = (const float*)d_in[2];
    float* out = (float*)d_out;

    const size_t basis_bytes = (size_t)B_DIM * KR * 2;              // 80 MiB
    const size_t wb_bytes    = (size_t)OUT_DIM * KR * 2;            // 40 MiB
    const size_t part8_bytes = (size_t)8 * OUT_ELEMS * 4;           // 64 MiB
    const size_t part4_bytes = (size_t)4 * OUT_ELEMS * 4;           // 32 MiB

    unsigned short* Ab = (unsigned short*)d_ws;
    unsigned short* Bb = (unsigned short*)((char*)d_ws + basis_bytes);
    float* part = (float*)((char*)d_ws + basis_bytes + wb_bytes);

    if (ws_size >= basis_bytes + wb_bytes + part4_bytes) {
        prep_kernel<<<dim3(NB_BASIS_BLK + NB_W_BLK), dim3(256), 0, stream>>>(
            x, (const float4*)W, knots, (unsigned int*)Ab, (uint4*)Bb);
        if (ws_size >= basis_bytes + wb_bytes + part8_bytes) {
            kan_gemm<8, false><<<dim3(B_DIM / TM, OUT_DIM / TN, 8), dim3(256), 0, stream>>>(
                Ab, Bb, part);
            kan_reduce<8><<<dim3(OUT_ELEMS / (256 * 4)), dim3(256), 0, stream>>>(part, out);
        } else {
            kan_gemm<4, false><<<dim3(B_DIM / TM, OUT_DIM / TN, 4), dim3(256), 0, stream>>>(
                Ab, Bb, part);
            kan_reduce<4><<<dim3(OUT_ELEMS / (256 * 4)), dim3(256), 0, stream>>>(part, out);
        }
    } else if (ws_size >= basis_bytes + wb_bytes) {
        zero_out_kernel<<<dim3(OUT_ELEMS / (256 * 4)), dim3(256), 0, stream>>>(out);
        prep_kernel<<<dim3(NB_BASIS_BLK + NB_W_BLK), dim3(256), 0, stream>>>(
            x, (const float4*)W, knots, (unsigned int*)Ab, (uint4*)Bb);
        kan_gemm<4, true><<<dim3(B_DIM / TM, OUT_DIM / TN, 4), dim3(256), 0, stream>>>(
            Ab, Bb, out);
    } else {
        kan_fallback<<<dim3(B_DIM, OUT_DIM / 256), dim3(256), 0, stream>>>(x, W, knots, out);
    }
}

// Round 5
// 285.277 us; speedup vs baseline: 1.0414x; 1.0414x over previous
//
#include <hip/hip_runtime.h>

#define B_DIM 2048
#define IN_DIM 1024
#define OUT_DIM 1024
#define K_KNOTS 20
#define KR (IN_DIM * K_KNOTS)   // 20480 reduction dim
#define TM 128
#define TN 128
#define BK 64
#define KSPLIT 4
#define KPB (KR / KSPLIT)       // 5120
#define OUT_ELEMS (B_DIM * OUT_DIM)
#define MT_TILES (B_DIM / TM)   // 16
#define NT_TILES (OUT_DIM / TN) // 8
#define GEMM_BLOCKS (MT_TILES * NT_TILES * KSPLIT)  // 512

#define NB_PAIRS (B_DIM * IN_DIM * K_KNOTS / 2)   // 20,971,520 bf16 pairs
#define NB_BASIS_BLK (NB_PAIRS / 256)             // 81920 blocks
#define NW4 (OUT_DIM * KR / 8)                    // 2,621,440 uint4 outputs
#define NB_W_BLK (NW4 / 256)                      // 10240 blocks

typedef __bf16 bf16x8 __attribute__((ext_vector_type(8)));
typedef float  f32x4  __attribute__((ext_vector_type(4)));

__device__ __forceinline__ unsigned short f2bf(float f) {
    unsigned int u = __float_as_uint(f);
    unsigned int r = u + 0x7fffu + ((u >> 16) & 1u);   // RNE; no NaN inputs here
    return (unsigned short)(r >> 16);
}

__device__ __forceinline__ unsigned int pack2(float lo, float hi) {
    return (unsigned int)f2bf(lo) | ((unsigned int)f2bf(hi) << 16);
}

__device__ __forceinline__ void async_load16(const void* g, void* l) {
    __builtin_amdgcn_global_load_lds(
        (const __attribute__((address_space(1))) void*)g,
        (__attribute__((address_space(3))) void*)l,
        16, 0, 0);
}

// ---------------- zero the output (atomic fallback path only) ----------------
__global__ void zero_out_kernel(float* out) {
    int idx = (blockIdx.x * 256 + threadIdx.x) * 4;
    float4 z = {0.f, 0.f, 0.f, 0.f};
    *(float4*)(out + idx) = z;
}

// ------- merged prep: basis bf16 (B,IN*K) + W fp32->bf16, one dispatch -------
__global__ void prep_kernel(const float* __restrict__ x,
                            const float4* __restrict__ Wsrc,
                            const float* __restrict__ knots,
                            unsigned int* __restrict__ basis_out,
                            uint4* __restrict__ w_out) {
    if (blockIdx.x < NB_BASIS_BLK) {
        unsigned int n = blockIdx.x * 256 + threadIdx.x;
        unsigned int p  = n % 10u;                      // which k-pair
        unsigned int bi = n / 10u;                      // b*1024 + i
        float xv   = x[bi];
        float invh = 1.0f / (knots[1] - knots[0]);
        float t0 = knots[2 * p], t1 = knots[2 * p + 1];
        float d0 = (xv - t0) * invh;
        float d1 = (xv - t1) * invh;
        float v0 = __expf(-0.5f * d0 * d0);
        float v1 = __expf(-0.5f * d1 * d1);
        basis_out[n] = pack2(v0, v1);
    } else {
        unsigned int t = (blockIdx.x - NB_BASIS_BLK) * 256 + threadIdx.x;
        float4 a = Wsrc[2 * t];
        float4 b = Wsrc[2 * t + 1];
        uint4 o;
        o.x = pack2(a.x, a.y);
        o.y = pack2(a.z, a.w);
        o.z = pack2(b.x, b.y);
        o.w = pack2(b.z, b.w);
        w_out[t] = o;
    }
}

// ---------------- bf16 MFMA GEMM: C[b,o] += sum_r A[b,r]*W[o,r] --------------
// LDS XOR swizzle keeps ds_read side conflict-free (verified R2: conflicts=0).
// XCD-aware remap: flat id -> (mt = 2*(id&7) + lsb, nt, z) so each XCD
// (empirical id%8 round-robin) owns 2 m-tiles x all n x all z = 64 blocks,
// exactly its co-resident set: A-tiles L2-resident (8x reuse), B 2x reuse.
template <int KS, bool ATOMIC>
__global__ void __launch_bounds__(256)
kan_gemm(const unsigned short* __restrict__ Ab,   // (2048, 20480) bf16 row-major
         const unsigned short* __restrict__ Bb,   // (1024, 20480) bf16 row-major
         float* __restrict__ out) {               // out or partial base
    __shared__ __align__(16) unsigned short As[TM * BK];
    __shared__ __align__(16) unsigned short Bs[TN * BK];

    const int KPBk = KR / KS;
    const int id   = blockIdx.x;
    const int xcd  = id & 7;
    const int ord  = id >> 3;           // 0..(GEMM_BLOCKS/8-1)
    const int mt   = xcd * 2 + (ord & 1);
    const int nt   = (ord >> 1) & (NT_TILES - 1);
    const int z    = ord >> (1 + 3);    // NT_TILES==8 -> 3 bits
    const int m0 = mt * TM;
    const int n0 = nt * TN;
    const int k0 = z * KPBk;

    const int tid  = threadIdx.x;
    const int wave = tid >> 6;
    const int lane = tid & 63;
    const int wm = wave & 1;          // 2x2 wave grid -> each wave does 64x64
    const int wn = wave >> 1;

    const int srow = lane >> 3;                 // staging: row within 8-row chunk
    const int scol = ((lane & 7) ^ srow) * 8;   // staging: swizzled element col

    f32x4 acc[4][4];
#pragma unroll
    for (int i = 0; i < 4; ++i)
#pragma unroll
        for (int j = 0; j < 4; ++j) acc[i][j] = (f32x4){0.f, 0.f, 0.f, 0.f};

    for (int kt = 0; kt < KPBk; kt += BK) {
        const int kb = k0 + kt;
        __syncthreads();   // previous iteration's ds_reads done before overwrite
#pragma unroll
        for (int c = 0; c < 4; ++c) {
            const int chunk = wave * 4 + c;            // 16 chunks of 8 rows
            const int r = chunk * 8 + srow;
            async_load16(Ab + (size_t)(m0 + r) * KR + kb + scol, &As[chunk * 512]);
            async_load16(Bb + (size_t)(n0 + r) * KR + kb + scol, &Bs[chunk * 512]);
        }
        __syncthreads();   // compiler drains vmcnt(0) before barrier

        const int quad = lane >> 4;
        const int r15  = lane & 15;
        const int r7   = lane & 7;
#pragma unroll
        for (int s = 0; s < 2; ++s) {
            const int cg = s * 4 + quad;               // colgroup 0..7
            const int xo = (cg ^ r7) * 8;              // unswizzled element offset
            bf16x8 af[4], bfv[4];
#pragma unroll
            for (int i = 0; i < 4; ++i) {
                af[i]  = *(const bf16x8*)&As[(wm * 64 + i * 16 + r15) * BK + xo];
                bfv[i] = *(const bf16x8*)&Bs[(wn * 64 + i * 16 + r15) * BK + xo];
            }
#pragma unroll
            for (int i = 0; i < 4; ++i)
#pragma unroll
                for (int j = 0; j < 4; ++j)
                    acc[i][j] = __builtin_amdgcn_mfma_f32_16x16x32_bf16(
                        af[i], bfv[j], acc[i][j], 0, 0, 0);
        }
    }

    // epilogue: C/D layout col=lane&15, row=(lane>>4)*4+reg
    float* dst = ATOMIC ? out : out + (size_t)z * OUT_ELEMS;
    const int quad = lane >> 4;
    const int col  = lane & 15;
#pragma unroll
    for (int i = 0; i < 4; ++i)
#pragma unroll
        for (int j = 0; j < 4; ++j)
#pragma unroll
            for (int r = 0; r < 4; ++r) {
                const int row = m0 + wm * 64 + i * 16 + quad * 4 + r;
                const int c   = n0 + wn * 64 + j * 16 + col;
                if (ATOMIC)
                    atomicAdd(&dst[(size_t)row * OUT_DIM + c], acc[i][j][r]);
                else
                    dst[(size_t)row * OUT_DIM + c] = acc[i][j][r];
            }
}

// ---------------- reduce KS partial slices -> out ----------------------------
template <int KS>
__global__ void kan_reduce(const float* __restrict__ part, float* __restrict__ out) {
    const int idx = (blockIdx.x * 256 + threadIdx.x) * 4;
    f32x4 s = *(const f32x4*)(part + idx);
#pragma unroll
    for (int z = 1; z < KS; ++z)
        s += *(const f32x4*)(part + (size_t)z * OUT_ELEMS + idx);
    *(f32x4*)(out + idx) = s;
}

// ---------------- fallback (ws too small): correctness-only fp32 -------------
__global__ void kan_fallback(const float* __restrict__ x,
                             const float* __restrict__ W,
                             const float* __restrict__ knots,
                             float* __restrict__ out) {
    __shared__ float basis[256 * K_KNOTS];
    const int b = blockIdx.x;
    const int o = blockIdx.y * blockDim.x + threadIdx.x;
    const float invh = 1.0f / (knots[1] - knots[0]);
    const float* w = W + (size_t)o * KR;
    float sum = 0.f;
    for (int i0 = 0; i0 < IN_DIM; i0 += 256) {
        __syncthreads();
        for (int idx = threadIdx.x; idx < 256 * K_KNOTS; idx += blockDim.x) {
            const int i = i0 + idx / K_KNOTS;
            const int k = idx % K_KNOTS;
            const float d = (x[(size_t)b * IN_DIM + i] - knots[k]) * invh;
            basis[idx] = __expf(-0.5f * d * d);
        }
        __syncthreads();
        for (int r = 0; r < 256 * K_KNOTS; ++r)
            sum += basis[r] * w[(size_t)i0 * K_KNOTS + r];
    }
    out[(size_t)b * OUT_DIM + o] = sum;
}

extern "C" void kernel_launch(void* const* d_in, const int* in_sizes, int n_in,
                              void* d_out, int out_size, void* d_ws, size_t ws_size,
                              hipStream_t stream) {
    const float* x     = (const float*)d_in[0];
    const float* W     = (const float*)d_in[1];
    const float* knots = (const float*)d_in[2];
    float* out = (float*)d_out;

    const size_t basis_bytes = (size_t)B_DIM * KR * 2;              // 80 MiB
    const size_t wb_bytes    = (size_t)OUT_DIM * KR * 2;            // 40 MiB
    const size_t part_bytes  = (size_t)KSPLIT * OUT_ELEMS * 4;      // 32 MiB

    unsigned short* Ab = (unsigned short*)d_ws;
    unsigned short* Bb = (unsigned short*)((char*)d_ws + basis_bytes);
    float* part = (float*)((char*)d_ws + basis_bytes + wb_bytes);

    if (ws_size >= basis_bytes + wb_bytes + part_bytes) {
        prep_kernel<<<dim3(NB_BASIS_BLK + NB_W_BLK), dim3(256), 0, stream>>>(
            x, (const float4*)W, knots, (unsigned int*)Ab, (uint4*)Bb);
        kan_gemm<KSPLIT, false><<<dim3(GEMM_BLOCKS), dim3(256), 0, stream>>>(Ab, Bb, part);
        kan_reduce<KSPLIT><<<dim3(OUT_ELEMS / (256 * 4)), dim3(256), 0, stream>>>(part, out);
    } else if (ws_size >= basis_bytes + wb_bytes) {
        zero_out_kernel<<<dim3(OUT_ELEMS / (256 * 4)), dim3(256), 0, stream>>>(out);
        prep_kernel<<<dim3(NB_BASIS_BLK + NB_W_BLK), dim3(256), 0, stream>>>(
            x, (const float4*)W, knots, (unsigned int*)Ab, (uint4*)Bb);
        kan_gemm<KSPLIT, true><<<dim3(GEMM_BLOCKS), dim3(256), 0, stream>>>(Ab, Bb, out);
    } else {
        kan_fallback<<<dim3(B_DIM, OUT_DIM / 256), dim3(256), 0, stream>>>(x, W, knots, out);
    }
}

// Round 6
// 260.860 us; speedup vs baseline: 1.1388x; 1.0936x over previous
//
#include <hip/hip_runtime.h>

#define B_DIM 2048
#define IN_DIM 1024
#define OUT_DIM 1024
#define K_KNOTS 20
#define KR (IN_DIM * K_KNOTS)   // 20480 reduction dim
#define TM 128
#define TN 128
#define BK 128
#define KSPLIT 4
#define KPB (KR / KSPLIT)       // 5120 -> 40 iters of BK=128
#define OUT_ELEMS (B_DIM * OUT_DIM)
#define MT_TILES (B_DIM / TM)   // 16
#define NT_TILES (OUT_DIM / TN) // 8
#define GEMM_BLOCKS (MT_TILES * NT_TILES * KSPLIT)  // 512

#define NB_QUADS (B_DIM * IN_DIM * 5)             // 10,485,760 threads (4 knots each)
#define NB_BASIS_BLK (NB_QUADS / 256)             // 40960 blocks
#define NW4 (OUT_DIM * KR / 8)                    // 2,621,440 uint4 outputs
#define NB_W_BLK (NW4 / 256)                      // 10240 blocks

typedef __bf16 bf16x8 __attribute__((ext_vector_type(8)));
typedef float  f32x4  __attribute__((ext_vector_type(4)));

__device__ __forceinline__ unsigned short f2bf(float f) {
    unsigned int u = __float_as_uint(f);
    unsigned int r = u + 0x7fffu + ((u >> 16) & 1u);   // RNE; no NaN inputs here
    return (unsigned short)(r >> 16);
}

__device__ __forceinline__ unsigned int pack2(float lo, float hi) {
    return (unsigned int)f2bf(lo) | ((unsigned int)f2bf(hi) << 16);
}

__device__ __forceinline__ void async_load16(const void* g, void* l) {
    __builtin_amdgcn_global_load_lds(
        (const __attribute__((address_space(1))) void*)g,
        (__attribute__((address_space(3))) void*)l,
        16, 0, 0);
}

// ---------------- zero the output (atomic fallback path only) ----------------
__global__ void zero_out_kernel(float* out) {
    int idx = (blockIdx.x * 256 + threadIdx.x) * 4;
    float4 z = {0.f, 0.f, 0.f, 0.f};
    *(float4*)(out + idx) = z;
}

// ------- merged prep: basis bf16 (B,IN*K) + W fp32->bf16, one dispatch -------
// basis: 1 thread per 4 consecutive knots (uint2 store, coalesced); knots
// computed analytically t_k = knots[0] + k*h (<=1ulp vs linspace, negligible
// vs bf16 rounding) -- removes per-lane knot gathers.
__global__ void __launch_bounds__(256) prep_kernel(
        const float* __restrict__ x,
        const float4* __restrict__ Wsrc,
        const float* __restrict__ knots,
        uint2* __restrict__ basis_out,
        uint4* __restrict__ w_out) {
    if (blockIdx.x < NB_BASIS_BLK) {
        unsigned int n = blockIdx.x * 256 + threadIdx.x;   // quad index
        unsigned int q  = n % 5u;                          // which knot-quad
        unsigned int bi = n / 5u;                          // b*1024 + i
        float t0 = knots[0];
        float h  = knots[1] - t0;
        float invh = 1.0f / h;
        float xv = x[bi];
        float k0 = (float)(4 * q);
        float v[4];
#pragma unroll
        for (int j = 0; j < 4; ++j) {
            float t = __builtin_fmaf(k0 + (float)j, h, t0);
            float d = (xv - t) * invh;
            v[j] = __expf(-0.5f * d * d);
        }
        uint2 o;
        o.x = pack2(v[0], v[1]);
        o.y = pack2(v[2], v[3]);
        basis_out[n] = o;
    } else {
        unsigned int t = (blockIdx.x - NB_BASIS_BLK) * 256 + threadIdx.x;
        float4 a = Wsrc[2 * t];
        float4 b = Wsrc[2 * t + 1];
        uint4 o;
        o.x = pack2(a.x, a.y);
        o.y = pack2(a.z, a.w);
        o.z = pack2(b.x, b.y);
        o.w = pack2(b.z, b.w);
        w_out[t] = o;
    }
}

// ---------------- bf16 MFMA GEMM: C[b,o] += sum_r A[b,r]*W[o,r] --------------
// BK=128: 40 K-iters (vs 80) -> half the barrier/vmcnt(0) drains, double the
// MFMA per barrier. LDS = 64 KB/block = 2 blocks/CU (grid already gives 2).
// XOR swizzle over 16 col-slots: lane stores global slot (s ^ row&7) at LDS
// slot s; reader fetches LDS slot (g ^ r7). Conflict-free family (R2: 0).
template <int KS, bool ATOMIC>
__global__ void __launch_bounds__(256)
kan_gemm(const unsigned short* __restrict__ Ab,   // (2048, 20480) bf16 row-major
         const unsigned short* __restrict__ Bb,   // (1024, 20480) bf16 row-major
         float* __restrict__ out) {               // out or partial base
    __shared__ __align__(16) unsigned short As[TM * BK];   // 32 KB
    __shared__ __align__(16) unsigned short Bs[TN * BK];   // 32 KB

    const int KPBk = KR / KS;
    const int id   = blockIdx.x;
    const int xcd  = id & 7;
    const int ord  = id >> 3;           // 0..63
    const int mt   = xcd * 2 + (ord & 1);
    const int nt   = (ord >> 1) & (NT_TILES - 1);
    const int z    = ord >> 4;          // 0..KS-1
    const int m0 = mt * TM;
    const int n0 = nt * TN;
    const int k0 = z * KPBk;

    const int tid  = threadIdx.x;
    const int wave = tid >> 6;
    const int lane = tid & 63;
    const int wm = wave & 1;          // 2x2 wave grid -> each wave does 64x64
    const int wn = wave >> 1;

    const int srow = lane >> 4;                       // row within 4-row chunk
    const int sslot = lane & 15;                      // LDS col-slot (16B units)

    f32x4 acc[4][4];
#pragma unroll
    for (int i = 0; i < 4; ++i)
#pragma unroll
        for (int j = 0; j < 4; ++j) acc[i][j] = (f32x4){0.f, 0.f, 0.f, 0.f};

    for (int kt = 0; kt < KPBk; kt += BK) {
        const int kb = k0 + kt;
        __syncthreads();   // previous iteration's ds_reads done before overwrite
#pragma unroll
        for (int c = 0; c < 8; ++c) {
            const int chunk = wave * 8 + c;            // 32 chunks of 4 rows
            const int r = chunk * 4 + srow;            // tile-local row 0..127
            const int gcol = ((sslot ^ (r & 7)) * 8);  // swizzled global col
            async_load16(Ab + (size_t)(m0 + r) * KR + kb + gcol, &As[chunk * 512]);
            async_load16(Bb + (size_t)(n0 + r) * KR + kb + gcol, &Bs[chunk * 512]);
        }
        __syncthreads();   // compiler drains vmcnt(0) before barrier

        const int quad = lane >> 4;
        const int r15  = lane & 15;
        const int r7   = lane & 7;
#pragma unroll
        for (int s = 0; s < 4; ++s) {
            const int g  = s * 4 + quad;               // global col-slot 0..15
            const int xo = (g ^ r7) * 8;               // LDS element offset
            bf16x8 af[4], bfv[4];
#pragma unroll
            for (int i = 0; i < 4; ++i) {
                af[i]  = *(const bf16x8*)&As[(wm * 64 + i * 16 + r15) * BK + xo];
                bfv[i] = *(const bf16x8*)&Bs[(wn * 64 + i * 16 + r15) * BK + xo];
            }
#pragma unroll
            for (int i = 0; i < 4; ++i)
#pragma unroll
                for (int j = 0; j < 4; ++j)
                    acc[i][j] = __builtin_amdgcn_mfma_f32_16x16x32_bf16(
                        af[i], bfv[j], acc[i][j], 0, 0, 0);
        }
    }

    // epilogue: C/D layout col=lane&15, row=(lane>>4)*4+reg
    float* dst = ATOMIC ? out : out + (size_t)z * OUT_ELEMS;
    const int quad = lane >> 4;
    const int col  = lane & 15;
#pragma unroll
    for (int i = 0; i < 4; ++i)
#pragma unroll
        for (int j = 0; j < 4; ++j)
#pragma unroll
            for (int r = 0; r < 4; ++r) {
                const int row = m0 + wm * 64 + i * 16 + quad * 4 + r;
                const int c   = n0 + wn * 64 + j * 16 + col;
                if (ATOMIC)
                    atomicAdd(&dst[(size_t)row * OUT_DIM + c], acc[i][j][r]);
                else
                    dst[(size_t)row * OUT_DIM + c] = acc[i][j][r];
            }
}

// ---------------- reduce KS partial slices -> out ----------------------------
template <int KS>
__global__ void kan_reduce(const float* __restrict__ part, float* __restrict__ out) {
    const int idx = (blockIdx.x * 256 + threadIdx.x) * 4;
    f32x4 s = *(const f32x4*)(part + idx);
#pragma unroll
    for (int z = 1; z < KS; ++z)
        s += *(const f32x4*)(part + (size_t)z * OUT_ELEMS + idx);
    *(f32x4*)(out + idx) = s;
}

// ---------------- fallback (ws too small): correctness-only fp32 -------------
__global__ void kan_fallback(const float* __restrict__ x,
                             const float* __restrict__ W,
                             const float* __restrict__ knots,
                             float* __restrict__ out) {
    __shared__ float basis[256 * K_KNOTS];
    const int b = blockIdx.x;
    const int o = blockIdx.y * blockDim.x + threadIdx.x;
    const float invh = 1.0f / (knots[1] - knots[0]);
    const float* w = W + (size_t)o * KR;
    float sum = 0.f;
    for (int i0 = 0; i0 < IN_DIM; i0 += 256) {
        __syncthreads();
        for (int idx = threadIdx.x; idx < 256 * K_KNOTS; idx += blockDim.x) {
            const int i = i0 + idx / K_KNOTS;
            const int k = idx % K_KNOTS;
            const float d = (x[(size_t)b * IN_DIM + i] - knots[k]) * invh;
            basis[idx] = __expf(-0.5f * d * d);
        }
        __syncthreads();
        for (int r = 0; r < 256 * K_KNOTS; ++r)
            sum += basis[r] * w[(size_t)i0 * K_KNOTS + r];
    }
    out[(size_t)b * OUT_DIM + o] = sum;
}

extern "C" void kernel_launch(void* const* d_in, const int* in_sizes, int n_in,
                              void* d_out, int out_size, void* d_ws, size_t ws_size,
                              hipStream_t stream) {
    const float* x     = (const float*)d_in[0];
    const float* W     = (const float*)d_in[1];
    const float* knots = (const float*)d_in[2];
    float* out = (float*)d_out;

    const size_t basis_bytes = (size_t)B_DIM * KR * 2;              // 80 MiB
    const size_t wb_bytes    = (size_t)OUT_DIM * KR * 2;            // 40 MiB
    const size_t part_bytes  = (size_t)KSPLIT * OUT_ELEMS * 4;      // 32 MiB

    unsigned short* Ab = (unsigned short*)d_ws;
    unsigned short* Bb = (unsigned short*)((char*)d_ws + basis_bytes);
    float* part = (float*)((char*)d_ws + basis_bytes + wb_bytes);

    if (ws_size >= basis_bytes + wb_bytes + part_bytes) {
        prep_kernel<<<dim3(NB_BASIS_BLK + NB_W_BLK), dim3(256), 0, stream>>>(
            x, (const float4*)W, knots, (uint2*)Ab, (uint4*)Bb);
        kan_gemm<KSPLIT, false><<<dim3(GEMM_BLOCKS), dim3(256), 0, stream>>>(Ab, Bb, part);
        kan_reduce<KSPLIT><<<dim3(OUT_ELEMS / (256 * 4)), dim3(256), 0, stream>>>(part, out);
    } else if (ws_size >= basis_bytes + wb_bytes) {
        zero_out_kernel<<<dim3(OUT_ELEMS / (256 * 4)), dim3(256), 0, stream>>>(out);
        prep_kernel<<<dim3(NB_BASIS_BLK + NB_W_BLK), dim3(256), 0, stream>>>(
            x, (const float4*)W, knots, (uint2*)Ab, (uint4*)Bb);
        kan_gemm<KSPLIT, true><<<dim3(GEMM_BLOCKS), dim3(256), 0, stream>>>(Ab, Bb, out);
    } else {
        kan_fallback<<<dim3(B_DIM, OUT_DIM / 256), dim3(256), 0, stream>>>(x, W, knots, out);
    }
}

// Round 8
// 256.640 us; speedup vs baseline: 1.1575x; 1.0164x over previous
//
#include <hip/hip_runtime.h>

#define B_DIM 2048
#define IN_DIM 1024
#define OUT_DIM 1024
#define K_KNOTS 20
#define KR (IN_DIM * K_KNOTS)   // 20480 reduction dim
#define TM 128
#define TN 128
#define BK 128
#define KSPLIT 4
#define KPB (KR / KSPLIT)       // 5120 -> 40 iters of BK=128
#define OUT_ELEMS (B_DIM * OUT_DIM)
#define MT_TILES (B_DIM / TM)   // 16
#define NT_TILES (OUT_DIM / TN) // 8
#define GEMM_BLOCKS (MT_TILES * NT_TILES * KSPLIT)  // 512

// LDS map (shorts): As half0 @0, As half1 @8192, Bs half0 @16384, Bs half1 @24576
#define LDS_AS0 0
#define LDS_AS1 8192
#define LDS_BS0 16384
#define LDS_BS1 24576

#define NB_QUADS (B_DIM * IN_DIM * 5)             // 10,485,760 threads (4 knots each)
#define NB_BASIS_BLK (NB_QUADS / 256)             // 40960 blocks
#define NW4 (OUT_DIM * KR / 8)                    // 2,621,440 uint4 outputs
#define NB_W_BLK (NW4 / 256)                      // 10240 blocks

typedef __bf16 bf16x8 __attribute__((ext_vector_type(8)));
typedef float  f32x4  __attribute__((ext_vector_type(4)));

__device__ __forceinline__ unsigned short f2bf(float f) {
    unsigned int u = __float_as_uint(f);
    unsigned int r = u + 0x7fffu + ((u >> 16) & 1u);   // RNE; no NaN inputs here
    return (unsigned short)(r >> 16);
}

__device__ __forceinline__ unsigned int pack2(float lo, float hi) {
    return (unsigned int)f2bf(lo) | ((unsigned int)f2bf(hi) << 16);
}

__device__ __forceinline__ void async_load16(const void* g, void* l) {
    __builtin_amdgcn_global_load_lds(
        (const __attribute__((address_space(1))) void*)g,
        (__attribute__((address_space(3))) void*)l,
        16, 0, 0);
}

// ---------------- zero the output (atomic fallback path only) ----------------
__global__ void zero_out_kernel(float* out) {
    int idx = (blockIdx.x * 256 + threadIdx.x) * 4;
    float4 z = {0.f, 0.f, 0.f, 0.f};
    *(float4*)(out + idx) = z;
}

// ------- merged prep: basis bf16 (B,IN*K) + W fp32->bf16, one dispatch -------
__global__ void __launch_bounds__(256) prep_kernel(
        const float* __restrict__ x,
        const float4* __restrict__ Wsrc,
        const float* __restrict__ knots,
        uint2* __restrict__ basis_out,
        uint4* __restrict__ w_out) {
    if (blockIdx.x < NB_BASIS_BLK) {
        unsigned int n = blockIdx.x * 256 + threadIdx.x;   // quad index
        unsigned int q  = n % 5u;                          // which knot-quad
        unsigned int bi = n / 5u;                          // b*1024 + i
        float t0 = knots[0];
        float h  = knots[1] - t0;
        float invh = 1.0f / h;
        float xv = x[bi];
        float k0 = (float)(4 * q);
        float v[4];
#pragma unroll
        for (int j = 0; j < 4; ++j) {
            float t = __builtin_fmaf(k0 + (float)j, h, t0);
            float d = (xv - t) * invh;
            v[j] = __expf(-0.5f * d * d);
        }
        uint2 o;
        o.x = pack2(v[0], v[1]);
        o.y = pack2(v[2], v[3]);
        basis_out[n] = o;
    } else {
        unsigned int t = (blockIdx.x - NB_BASIS_BLK) * 256 + threadIdx.x;
        float4 a = Wsrc[2 * t];
        float4 b = Wsrc[2 * t + 1];
        uint4 o;
        o.x = pack2(a.x, a.y);
        o.y = pack2(a.z, a.w);
        o.z = pack2(b.x, b.y);
        o.w = pack2(b.z, b.w);
        w_out[t] = o;
    }
}

// ---------------- bf16 MFMA GEMM: C[b,o] += sum_r A[b,r]*W[o,r] --------------
// BK=128 staged as TWO 64-col half-tiles, each byte-identical to the R3/R5
// layout that measured 0 bank conflicts (row stride 64 shorts, 8 col-slots,
// XOR swizzle (lane&7)^srow). Flat single __shared__ block + explicit offsets
// (R7's 2-D-array variant of the same map core-dumped; this is the hardened
// expression of the identical memory layout).
template <int KS, bool ATOMIC>
__global__ void __launch_bounds__(256)
kan_gemm(const unsigned short* __restrict__ Ab,   // (2048, 20480) bf16 row-major
         const unsigned short* __restrict__ Bb,   // (1024, 20480) bf16 row-major
         float* __restrict__ out) {               // out or partial base
    __shared__ __align__(16) unsigned short lds[32768];   // 64 KB

    const int KPBk = KR / KS;
    const int id   = blockIdx.x;
    const int xcd  = id & 7;
    const int ord  = id >> 3;           // 0..63
    const int mt   = xcd * 2 + (ord & 1);
    const int nt   = (ord >> 1) & (NT_TILES - 1);
    const int z    = ord >> 4;          // 0..KS-1
    const int m0 = mt * TM;
    const int n0 = nt * TN;
    const int k0 = z * KPBk;

    const int tid  = threadIdx.x;
    const int wave = tid >> 6;
    const int lane = tid & 63;
    const int wm = wave & 1;          // 2x2 wave grid -> each wave does 64x64
    const int wn = wave >> 1;

    const int srow = lane >> 3;                 // staging: row within 8-row chunk
    const int scol = ((lane & 7) ^ srow) * 8;   // staging: swizzled element col

    f32x4 acc[4][4];
#pragma unroll
    for (int i = 0; i < 4; ++i)
#pragma unroll
        for (int j = 0; j < 4; ++j) acc[i][j] = (f32x4){0.f, 0.f, 0.f, 0.f};

    for (int kt = 0; kt < KPBk; kt += BK) {
        const int kb = k0 + kt;
        __syncthreads();   // previous iteration's ds_reads done before overwrite
#pragma unroll
        for (int c = 0; c < 4; ++c) {
            const int chunk = wave * 4 + c;            // 16 chunks of 8 rows
            const int r = chunk * 8 + srow;
            const unsigned short* arow = Ab + (size_t)(m0 + r) * KR + kb + scol;
            const unsigned short* brow = Bb + (size_t)(n0 + r) * KR + kb + scol;
            unsigned short* slot = &lds[chunk * 512];
            async_load16(arow,      slot + LDS_AS0);
            async_load16(arow + 64, slot + LDS_AS1);
            async_load16(brow,      slot + LDS_BS0);
            async_load16(brow + 64, slot + LDS_BS1);
        }
        __syncthreads();   // compiler drains vmcnt(0) before barrier

        const int quad = lane >> 4;
        const int r15  = lane & 15;
        const int r7   = lane & 7;
#pragma unroll
        for (int s = 0; s < 4; ++s) {
            const int abase = (s >> 1) ? LDS_AS1 : LDS_AS0;
            const int bbase = (s >> 1) ? LDS_BS1 : LDS_BS0;
            const int cg = (s & 1) * 4 + quad;         // colgroup 0..7 in half
            const int xo = (cg ^ r7) * 8;              // unswizzled element offset
            bf16x8 af[4], bfv[4];
#pragma unroll
            for (int i = 0; i < 4; ++i) {
                af[i]  = *(const bf16x8*)&lds[abase + (wm * 64 + i * 16 + r15) * 64 + xo];
                bfv[i] = *(const bf16x8*)&lds[bbase + (wn * 64 + i * 16 + r15) * 64 + xo];
            }
#pragma unroll
            for (int i = 0; i < 4; ++i)
#pragma unroll
                for (int j = 0; j < 4; ++j)
                    acc[i][j] = __builtin_amdgcn_mfma_f32_16x16x32_bf16(
                        af[i], bfv[j], acc[i][j], 0, 0, 0);
        }
    }

    // epilogue: C/D layout col=lane&15, row=(lane>>4)*4+reg
    float* dst = ATOMIC ? out : out + (size_t)z * OUT_ELEMS;
    const int quad = lane >> 4;
    const int col  = lane & 15;
#pragma unroll
    for (int i = 0; i < 4; ++i)
#pragma unroll
        for (int j = 0; j < 4; ++j)
#pragma unroll
            for (int r = 0; r < 4; ++r) {
                const int row = m0 + wm * 64 + i * 16 + quad * 4 + r;
                const int c   = n0 + wn * 64 + j * 16 + col;
                if (ATOMIC)
                    atomicAdd(&dst[(size_t)row * OUT_DIM + c], acc[i][j][r]);
                else
                    dst[(size_t)row * OUT_DIM + c] = acc[i][j][r];
            }
}

// ---------------- reduce KS partial slices -> out ----------------------------
template <int KS>
__global__ void kan_reduce(const float* __restrict__ part, float* __restrict__ out) {
    const int idx = (blockIdx.x * 256 + threadIdx.x) * 4;
    f32x4 s = *(const f32x4*)(part + idx);
#pragma unroll
    for (int z = 1; z < KS; ++z)
        s += *(const f32x4*)(part + (size_t)z * OUT_ELEMS + idx);
    *(f32x4*)(out + idx) = s;
}

// ---------------- fallback (ws too small): correctness-only fp32 -------------
__global__ void kan_fallback(const float* __restrict__ x,
                             const float* __restrict__ W,
                             const float* __restrict__ knots,
                             float* __restrict__ out) {
    __shared__ float basis[256 * K_KNOTS];
    const int b = blockIdx.x;
    const int o = blockIdx.y * blockDim.x + threadIdx.x;
    const float invh = 1.0f / (knots[1] - knots[0]);
    const float* w = W + (size_t)o * KR;
    float sum = 0.f;
    for (int i0 = 0; i0 < IN_DIM; i0 += 256) {
        __syncthreads();
        for (int idx = threadIdx.x; idx < 256 * K_KNOTS; idx += blockDim.x) {
            const int i = i0 + idx / K_KNOTS;
            const int k = idx % K_KNOTS;
            const float d = (x[(size_t)b * IN_DIM + i] - knots[k]) * invh;
            basis[idx] = __expf(-0.5f * d * d);
        }
        __syncthreads();
        for (int r = 0; r < 256 * K_KNOTS; ++r)
            sum += basis[r] * w[(size_t)i0 * K_KNOTS + r];
    }
    out[(size_t)b * OUT_DIM + o] = sum;
}

extern "C" void kernel_launch(void* const* d_in, const int* in_sizes, int n_in,
                              void* d_out, int out_size, void* d_ws, size_t ws_size,
                              hipStream_t stream) {
    const float* x     = (const float*)d_in[0];
    const float* W     = (const float*)d_in[1];
    const float* knots = (const float*)d_in[2];
    float* out = (float*)d_out;

    const size_t basis_bytes = (size_t)B_DIM * KR * 2;              // 80 MiB
    const size_t wb_bytes    = (size_t)OUT_DIM * KR * 2;            // 40 MiB
    const size_t part_bytes  = (size_t)KSPLIT * OUT_ELEMS * 4;      // 32 MiB

    unsigned short* Ab = (unsigned short*)d_ws;
    unsigned short* Bb = (unsigned short*)((char*)d_ws + basis_bytes);
    float* part = (float*)((char*)d_ws + basis_bytes + wb_bytes);

    if (ws_size >= basis_bytes + wb_bytes + part_bytes) {
        prep_kernel<<<dim3(NB_BASIS_BLK + NB_W_BLK), dim3(256), 0, stream>>>(
            x, (const float4*)W, knots, (uint2*)Ab, (uint4*)Bb);
        kan_gemm<KSPLIT, false><<<dim3(GEMM_BLOCKS), dim3(256), 0, stream>>>(Ab, Bb, part);
        kan_reduce<KSPLIT><<<dim3(OUT_ELEMS / (256 * 4)), dim3(256), 0, stream>>>(part, out);
    } else if (ws_size >= basis_bytes + wb_bytes) {
        zero_out_kernel<<<dim3(OUT_ELEMS / (256 * 4)), dim3(256), 0, stream>>>(out);
        prep_kernel<<<dim3(NB_BASIS_BLK + NB_W_BLK), dim3(256), 0, stream>>>(
            x, (const float4*)W, knots, (uint2*)Ab, (uint4*)Bb);
        kan_gemm<KSPLIT, true><<<dim3(GEMM_BLOCKS), dim3(256), 0, stream>>>(Ab, Bb, out);
    } else {
        kan_fallback<<<dim3(B_DIM, OUT_DIM / 256), dim3(256), 0, stream>>>(x, W, knots, out);
    }
}